// Round 12
// baseline (59.138 us; speedup 1.0000x reference)
//
#include <hip/hip_runtime.h>
#include <hip/hip_bf16.h>
#include <math.h>

// Problem constants (B=64, T=512, D=1024 from reference setup)
constexpr int   Bc       = 64;
constexpr int   Tc       = 512;
constexpr int   Dc       = 1024;
constexpr int   NMc      = 5;
constexpr int   TvC      = Tc - NMc - 1;   // 506
constexpr float TEMP_INV = 10.0f;

using f32x4 = __attribute__((ext_vector_type(4))) float;
using i32x4 = __attribute__((ext_vector_type(4))) int;
using i32x8 = __attribute__((ext_vector_type(8))) int;

__device__ inline float wave_reduce_sum(float v) {
#pragma unroll
    for (int off = 32; off; off >>= 1) v += __shfl_xor(v, off);
    return v;
}

// float -> OCP e4m3fn, round-to-nearest-even (manual; self-contained).
__device__ inline unsigned char f2e4m3(float f) {
    unsigned u = __float_as_uint(f);
    unsigned s = (u >> 24) & 0x80u;
    float a = __uint_as_float(u & 0x7fffffffu);
    if (a >= 448.f) return (unsigned char)(s | 0x7Eu);    // clamp (never hit here)
    int Ef = (int)((u >> 23) & 0xFFu) - 127;
    unsigned r;
    if (Ef < -6) {                       // subnormal: step 2^-9
        int n = (int)rintf(a * 512.0f);  // RNE, 0..8
        r = (unsigned)n;                 // n==8 -> 0x08 == min normal 2^-6
    } else {
        unsigned m23 = u & 0x7fffffu;
        unsigned m = (m23 + 0x7ffffu + ((m23 >> 20) & 1u)) >> 20;  // RNE to 3 bits
        int E = Ef + 7;
        if (m == 8u) { m = 0u; E += 1; } // mantissa carry
        r = ((unsigned)E << 3) | m;
    }
    return (unsigned char)(s | r);
}

#define GLOAD16(gp, lp)                                                        \
    __builtin_amdgcn_global_load_lds(                                          \
        (const __attribute__((address_space(1))) void*)(gp),                   \
        (__attribute__((address_space(3))) void*)(lp), 16, 0, 0)

// ---------------------------------------------------------------------------
// Kernel 1: normalize rows -> fp8 e4m3 feats. Wave-per-row, no LDS/barriers.
// Also zeroes the output accumulator (block 0): stream-ordered before combine.
__global__ __launch_bounds__(256) void tcl_prep(const float* __restrict__ h,
                                                unsigned char* __restrict__ fq,
                                                float* __restrict__ out) {
    if (blockIdx.x == 0 && threadIdx.x == 0) *out = 0.f;
    const int row  = blockIdx.x * 4 + (threadIdx.x >> 6);
    const int lane = threadIdx.x & 63;
    const float4* h4 = reinterpret_cast<const float4*>(h) + (size_t)row * 256 + lane;
    float4 v[4];
    float ss = 0.f;
#pragma unroll
    for (int i = 0; i < 4; ++i) {
        v[i] = h4[i * 64];
        ss += v[i].x*v[i].x + v[i].y*v[i].y + v[i].z*v[i].z + v[i].w*v[i].w;
    }
    ss = wave_reduce_sum(ss);                       // all lanes hold total
    const float inv = 1.0f / fmaxf(sqrtf(ss), 1e-12f);
    unsigned* o4 = reinterpret_cast<unsigned*>(fq + (size_t)row * Dc);
#pragma unroll
    for (int i = 0; i < 4; ++i) {
        const unsigned pk = (unsigned)f2e4m3(v[i].x * inv)
                          | ((unsigned)f2e4m3(v[i].y * inv) << 8)
                          | ((unsigned)f2e4m3(v[i].z * inv) << 16)
                          | ((unsigned)f2e4m3(v[i].w * inv) << 24);
        o4[lane + i * 64] = pk;                     // element base lane*4+i*256
    }
}

// ---------------------------------------------------------------------------
// Kernel 2: MX-scaled fp8 MFMA negative-score pass + fused positive extract.
// R11 structure verbatim (jobs, grid, LDS bytes, 2-barrier loop), but MFMA =
// mfma_scale_f32_16x16x128_f8f6f4 with unity E8M0 scales (0x7F = 1.0): K=128
// per instruction -> 64 MFMA/wave instead of 256 (2x rate, 4x fewer chain
// links), and the per-step ksub loop disappears. Fragment = 32 contiguous
// K-bytes/lane = two 16-B granules; with the 16-B-granule XOR swizzle these
// are two ds_read_b128 at loop-invariant offsets. Staging byte-identical to
// R11 (pre-swizzled global source, linear LDS dest). C/D layout is shape-
// determined (m127/m128) so the epilogue/harvest is untouched.
// Fixed-ref logsumexp: scores 10*cos in [-10,10] => S += exp(sc-10).
// S_part[b][sj][t] write-once; positives fused (pos_d diag, pos_x boundary).
__device__ __constant__ unsigned char JOB_TI[20] =
    {0,1, 0,1,2,3, 0,1,2,3,4,5, 0,1,2,3,4,5,6,7};
__device__ __constant__ unsigned char JOB_SJ[20] =
    {0,0, 1,1,1,1, 2,2,2,2,2,2, 3,3,3,3,3,3,3,3};

__global__ __launch_bounds__(256) void tcl_scores(const unsigned char* __restrict__ fq,
                                                  float* __restrict__ S_part,
                                                  float* __restrict__ pos_d,
                                                  float* __restrict__ pos_x) {
    // XCD-chunked swizzle: p%8 = XCD chunk; each batch's 20 jobs share an XCD.
    const int p  = blockIdx.x;
    const int b  = (p & 7) * 8 + ((p >> 3) / 20);
    const int j  = (p >> 3) % 20;
    const int ti = (int)JOB_TI[j];
    const int sj = (int)JOB_SJ[j];
    const int t0 = ti * 64;
    const int s0 = sj * 128;
    const bool is_diag = (ti == 2 * sj) || (ti == 2 * sj + 1);
    const bool is_x    = (ti == 2 * sj - 1);

    const unsigned char* f = fq + (size_t)b * Tc * Dc;
    const int lane = threadIdx.x & 63;
    const int wid  = threadIdx.x >> 6;
    const int wr   = wid >> 1, wc = wid & 1;

    __shared__ __align__(16) unsigned char Als[64 * 128];    //  8 KB
    __shared__ __align__(16) unsigned char Bls[128 * 128];   // 16 KB

    // ---- staging (byte-identical to R11): region = 1 KB = 8 rows x 128 B;
    // lane l -> row sub=l>>3, 16-B granule c8=l&7; source granule XOR-permuted.
    const int sub = lane >> 3;
    const int c8  = lane & 7;
    const int cswb = (c8 ^ sub) << 4;
    const unsigned char* gA[2]; const unsigned char* gB[4];
    int lAo[2]; int lBo[4];
#pragma unroll
    for (int i = 0; i < 2; ++i) {
        const int ri = wid * 2 + i;               // 0..7
        gA[i] = f + (size_t)(t0 + ri * 8 + sub) * Dc + cswb;
        lAo[i] = ri * 1024;
    }
#pragma unroll
    for (int i = 0; i < 4; ++i) {
        const int ri = wid * 4 + i;               // 0..15
        gB[i] = f + (size_t)(s0 + ri * 8 + sub) * Dc + cswb;
        lBo[i] = ri * 1024;
    }

    // ---- fragment read offsets (bytes), loop-invariant, swizzle-matched ----
    // Lane (r16, kg) reads row r16's K-bytes [kg*32, kg*32+32): granules
    // 2kg, 2kg+1, each XORed with (r16&7).
    const int r16 = lane & 15, kg = lane >> 4;
    const int xk  = r16 & 7;
    const int o0  = ((2 * kg)     ^ xk) << 4;
    const int o1  = ((2 * kg + 1) ^ xk) << 4;
    int aoff[2][2], boff[4][2];
#pragma unroll
    for (int q = 0; q < 2; ++q) {
        const int rb = (wr * 32 + q * 16 + r16) * 128;
        aoff[q][0] = rb + o0; aoff[q][1] = rb + o1;
    }
#pragma unroll
    for (int q = 0; q < 4; ++q) {
        const int rb = (wc * 64 + q * 16 + r16) * 128;
        boff[q][0] = rb + o0; boff[q][1] = rb + o1;
    }

    f32x4 acc[2][4];
#pragma unroll
    for (int fa = 0; fa < 2; ++fa)
#pragma unroll
        for (int fbj = 0; fbj < 4; ++fbj) acc[fa][fbj] = f32x4{0.f, 0.f, 0.f, 0.f};

    // ---- K loop: 8 steps of 128 fp8-bytes, single-buffered, 2 barriers ----
    for (int kt = 0; kt < 8; ++kt) {
#pragma unroll
        for (int i = 0; i < 2; ++i) { GLOAD16(gA[i], Als + lAo[i]); gA[i] += 128; }
#pragma unroll
        for (int i = 0; i < 4; ++i) { GLOAD16(gB[i], Bls + lBo[i]); gB[i] += 128; }
        __syncthreads();   // drains vmcnt -> LDS tiles ready

        i32x8 av[2], bv[4];
#pragma unroll
        for (int q = 0; q < 2; ++q) {
            i32x4 lo = *(const i32x4*)(Als + aoff[q][0]);
            i32x4 hi = *(const i32x4*)(Als + aoff[q][1]);
            av[q] = __builtin_shufflevector(lo, hi, 0, 1, 2, 3, 4, 5, 6, 7);
        }
#pragma unroll
        for (int q = 0; q < 4; ++q) {
            i32x4 lo = *(const i32x4*)(Bls + boff[q][0]);
            i32x4 hi = *(const i32x4*)(Bls + boff[q][1]);
            bv[q] = __builtin_shufflevector(lo, hi, 0, 1, 2, 3, 4, 5, 6, 7);
        }
#pragma unroll
        for (int fa = 0; fa < 2; ++fa)
#pragma unroll
            for (int fbj = 0; fbj < 4; ++fbj)
                acc[fa][fbj] = __builtin_amdgcn_mfma_scale_f32_16x16x128_f8f6f4(
                    av[fa], bv[fbj], acc[fa][fbj],
                    0, 0,                 // cbsz/blgp: FMT fp8-e4m3 for A and B
                    0, 0x7F7F7F7F,        // scale_a opsel/byte: E8M0 1.0
                    0, 0x7F7F7F7F);       // scale_b
        __syncthreads();   // all reads done before next stage overwrites
    }

    // ---- epilogue: exp-sum (masked) + positive row-side harvest ----
    __shared__ float S_sh[2][64];
    __shared__ float P_sh[2][64];
#pragma unroll
    for (int fa = 0; fa < 2; ++fa) {
#pragma unroll
        for (int r = 0; r < 4; ++r) {
            const int trow = t0 + wr * 32 + fa * 16 + kg * 4 + r;
            float v = 0.f, pv = 0.f;
#pragma unroll
            for (int fbj = 0; fbj < 4; ++fbj) {
                const int col = s0 + wc * 64 + fbj * 16 + r16;
                const float sc = acc[fa][fbj][r] * TEMP_INV;
                v += (col >= trow + NMc) ? __expf(sc - 10.f) : 0.f;
                const int dd = col - trow;
                pv += (dd * dd == 1 || dd * dd == 4) ? sc : 0.f;
            }
#pragma unroll
            for (int off = 1; off < 16; off <<= 1) {
                v  += __shfl_xor(v, off);
                pv += __shfl_xor(pv, off);
            }
            if (r16 == 0) {
                const int rl = wr * 32 + fa * 16 + kg * 4 + r;
                S_sh[wc][rl] = v;
                P_sh[wc][rl] = pv;
            }
        }
    }

    // ---- col-side positive harvest (x-jobs only) ----
    // Pairs (u, v): u = t0+62/63 (rows), v = s0/s0+1 (cols); value = sc(u,v)
    // feeds pos[v]. Rows 62/63 live in wave wr=1; cols s0/s0+1 in wc=0, fbj=0.
    if (is_x && wr == 1 && wc == 0) {
        float cv = 0.f;
        const int c = s0 + r16;
#pragma unroll
        for (int fa = 0; fa < 2; ++fa)
#pragma unroll
            for (int r = 0; r < 4; ++r) {
                const int trow = t0 + 32 + fa * 16 + kg * 4 + r;
                const int dd = c - trow;
                cv += (dd == 1 || dd == 2) ? acc[fa][0][r] * TEMP_INV : 0.f;
            }
        cv += __shfl_xor(cv, 16);
        cv += __shfl_xor(cv, 32);
        if (kg == 0 && r16 < 2) pos_x[(size_t)b * Tc + c] = cv;
    }

    __syncthreads();
    if (threadIdx.x < 64) {
        const int t = t0 + threadIdx.x;
        S_part[((size_t)b * 4 + sj) * Tc + t] = S_sh[0][threadIdx.x] + S_sh[1][threadIdx.x];
        const float pr = P_sh[0][threadIdx.x] + P_sh[1][threadIdx.x];
        if (is_diag)
            pos_d[(size_t)b * Tc + t] = pr;
        if (is_x && threadIdx.x >= 62)             // rows t0+62, t0+63
            pos_x[(size_t)b * Tc + t] = pr;
    }
}

// ---------------------------------------------------------------------------
// Kernel 3: trivial combine. One block per batch; reads S_part slices + pos
// tables, closes the logsumexp, block-reduce, ONE atomicAdd per block.
__global__ __launch_bounds__(256) void tcl_combine(const float* __restrict__ S_part,
                                                   const float* __restrict__ pos_d,
                                                   const float* __restrict__ pos_x,
                                                   float* __restrict__ out, float scale) {
    const int b = blockIdx.x;
    float lsum = 0.f;
    for (int t = threadIdx.x; t < TvC; t += 256) {
        const int ti = t >> 7, tl = t & 127;
        float S = 0.f;
        for (int sj = ti; sj < 4; ++sj) S += S_part[((size_t)b * 4 + sj) * Tc + t];
        float praw = pos_d[(size_t)b * Tc + t];
        if ((tl >= 126 && ti < 3) || (tl <= 1 && ti > 0))
            praw += pos_x[(size_t)b * Tc + t];
        const float cnt = (t == 0) ? 2.f : (t == 1) ? 3.f : 4.f;
        const float pos = praw / cnt;
        lsum += __logf(__expf(pos - 10.f) + S) + 10.f - pos;
    }
    lsum = wave_reduce_sum(lsum);
    __shared__ float wls[4];
    const int lane = threadIdx.x & 63, wid = threadIdx.x >> 6;
    if (lane == 0) wls[wid] = lsum;
    __syncthreads();
    if (threadIdx.x == 0)
        atomicAdd(out, (wls[0] + wls[1] + wls[2] + wls[3]) * scale);
}

// ---------------------------------------------------------------------------
extern "C" void kernel_launch(void* const* d_in, const int* in_sizes, int n_in,
                              void* d_out, int out_size, void* d_ws, size_t ws_size,
                              hipStream_t stream) {
    const float* h = (const float*)d_in[0];
    float* out = (float*)d_out;

    const size_t feats_bytes = (size_t)Bc * Tc * Dc;                   // 32 MiB
    const size_t spart_bytes = (size_t)Bc * 4 * Tc * sizeof(float);    // 512 KiB
    const size_t posd_bytes  = (size_t)Bc * Tc * sizeof(float);        // 128 KiB
    const float  scale       = 1.0f / (float)(Bc * TvC);

    unsigned char* fq = (unsigned char*)d_ws;
    float* S_part = (float*)((char*)d_ws + feats_bytes);
    float* pos_d  = (float*)((char*)d_ws + feats_bytes + spart_bytes);
    float* pos_x  = (float*)((char*)d_ws + feats_bytes + spart_bytes + posd_bytes);

    tcl_prep<<<Bc * Tc / 4, 256, 0, stream>>>(h, fq, out);
    tcl_scores<<<Bc * 20, 256, 0, stream>>>(fq, S_part, pos_d, pos_x);
    tcl_combine<<<Bc, 256, 0, stream>>>(S_part, pos_d, pos_x, out, scale);
    (void)ws_size; (void)in_sizes; (void)n_in; (void)out_size;
}